// Round 2
// baseline (208.882 us; speedup 1.0000x reference)
//
#include <hip/hip_runtime.h>
#include <math.h>

#define TILE 64
#define RAD  8
#define IW   (TILE + 2*RAD)   // 80
#define KS   17
#define IMG  512

struct GaussW { float w[KS]; };

__global__ __launch_bounds__(256) void GaussianBlur_38963943309988_kernel(
    const float* __restrict__ in, float* __restrict__ out, GaussW gw, int nimg)
{
    __shared__ __align__(16) float s_raw[IW * IW];   // 80x80 scaled input tile
    __shared__ __align__(16) float s_h[IW * TILE];   // 80 rows x 64 cols after horizontal pass

    const int tx  = blockIdx.x;          // tile col 0..7
    const int ty  = blockIdx.y;          // tile row 0..7
    const int img = blockIdx.z;          // 0..95
    const float* __restrict__ src = in  + (size_t)img * IMG * IMG;
    float* __restrict__       dst = out + (size_t)img * IMG * IMG;
    const int x0 = tx * TILE - RAD;
    const int y0 = ty * TILE - RAD;
    const int t  = threadIdx.x;

    // ---------- phase 1: global -> LDS, scale to [0,255] ----------
    const bool interior = (x0 >= 0) && (x0 + IW <= IMG) && (y0 >= 0) && (y0 + IW <= IMG);
    if (interior) {
        // 80 rows x 20 float4 (x0-8 is a multiple of 4 floats -> 16B aligned)
        for (int idx = t; idx < IW * (IW/4); idx += 256) {
            const int row = idx / (IW/4);
            const int c4  = idx - row * (IW/4);
            const float4 v = *reinterpret_cast<const float4*>(
                src + (size_t)(y0 + row) * IMG + (x0 + 4*c4));
            float4 r;
            r.x = (v.x + 1.0f) * 127.5f;
            r.y = (v.y + 1.0f) * 127.5f;
            r.z = (v.z + 1.0f) * 127.5f;
            r.w = (v.w + 1.0f) * 127.5f;
            *reinterpret_cast<float4*>(&s_raw[row*IW + 4*c4]) = r;
        }
    } else {
        for (int idx = t; idx < IW*IW; idx += 256) {
            const int row = idx / IW;
            const int col = idx - row*IW;
            int gx = x0 + col;
            int gy = y0 + row;
            gx = gx < 0 ? -gx : (gx >= IMG ? 2*IMG - 2 - gx : gx);  // reflect_101
            gy = gy < 0 ? -gy : (gy >= IMG ? 2*IMG - 2 - gy : gy);
            const float v = src[(size_t)gy*IMG + gx];
            s_raw[idx] = (v + 1.0f) * 127.5f;
        }
    }
    __syncthreads();

    // ---------- phase 2: horizontal blur (80 rows x 64 cols), 4 cols/thread ----------
    {
        const int tc = t & 15;    // column group: cols 4tc..4tc+3
        const int tr = t >> 4;    // 0..15
        #pragma unroll
        for (int rr = 0; rr < 5; ++rr) {
            const int row = tr + rr*16;
            const float* rp = &s_raw[row*IW + 4*tc];
            float win[20];
            #pragma unroll
            for (int j = 0; j < 5; ++j) {
                const float4 v = *reinterpret_cast<const float4*>(rp + 4*j);
                win[4*j+0] = v.x; win[4*j+1] = v.y; win[4*j+2] = v.z; win[4*j+3] = v.w;
            }
            float4 acc = {0.f, 0.f, 0.f, 0.f};
            #pragma unroll
            for (int k = 0; k < KS; ++k) {
                const float w = gw.w[k];
                acc.x += w * win[k+0];
                acc.y += w * win[k+1];
                acc.z += w * win[k+2];
                acc.w += w * win[k+3];
            }
            *reinterpret_cast<float4*>(&s_h[row*TILE + 4*tc]) = acc;
        }
    }
    __syncthreads();

    // ---------- phase 3: vertical blur + affine + store ----------
    {
        const int tc = t & 15;    // cols 4tc..4tc+3
        const int tr = t >> 4;    // rows 4tr..4tr+3
        float4 rows[20];
        #pragma unroll
        for (int k = 0; k < 20; ++k)
            rows[k] = *reinterpret_cast<const float4*>(&s_h[(4*tr + k)*TILE + 4*tc]);
        const int ox = tx*TILE + 4*tc;
        #pragma unroll
        for (int rj = 0; rj < 4; ++rj) {
            float4 acc = {0.f, 0.f, 0.f, 0.f};
            #pragma unroll
            for (int k = 0; k < KS; ++k) {
                const float w = gw.w[k];
                const float4 v = rows[rj + k];
                acc.x += w * v.x;
                acc.y += w * v.y;
                acc.z += w * v.z;
                acc.w += w * v.w;
            }
            const int oy = ty*TILE + 4*tr + rj;
            float4 o;
            o.x = acc.x * (2.0f/255.0f) - (1.0f/255.0f);
            o.y = acc.y * (2.0f/255.0f) - (1.0f/255.0f);
            o.z = acc.z * (2.0f/255.0f) - (1.0f/255.0f);
            o.w = acc.w * (2.0f/255.0f) - (1.0f/255.0f);
            *reinterpret_cast<float4*>(dst + (size_t)oy*IMG + ox) = o;
        }
    }
    (void)nimg;
}

extern "C" void kernel_launch(void* const* d_in, const int* in_sizes, int n_in,
                              void* d_out, int out_size, void* d_ws, size_t ws_size,
                              hipStream_t stream) {
    const float* in = (const float*)d_in[0];
    float* out = (float*)d_out;

    // Gaussian weights: matches cv2.getGaussianKernel(17, 2) / the jnp reference
    GaussW gw;
    double g[KS], s = 0.0;
    for (int i = 0; i < KS; ++i) {
        const double d = i - (KS - 1) / 2.0;
        g[i] = exp(-(d * d) / (2.0 * 2.0 * 2.0));  // 2*sigma^2 = 8
        s += g[i];
    }
    for (int i = 0; i < KS; ++i) gw.w[i] = (float)(g[i] / s);

    const int nimg = in_sizes[0] / (IMG * IMG);   // 32*3 = 96
    dim3 grid(IMG / TILE, IMG / TILE, nimg);      // (8, 8, 96)
    dim3 block(256);
    hipLaunchKernelGGL(GaussianBlur_38963943309988_kernel, grid, block, 0, stream,
                       in, out, gw, nimg);
}

// Round 7
// 195.130 us; speedup vs baseline: 1.0705x; 1.0705x over previous
//
#include <hip/hip_runtime.h>
#include <math.h>

#define TILE 64
#define RAD  8
#define IW   (TILE + 2*RAD)   // 80
#define IW4  (IW/4)           // 20 float4 chunks per raw row
#define HST  68                // s_h row stride in floats (64+4 pad: kills bank conflicts)
#define KS   17
#define IMG  512

struct GaussW { float w[KS]; };

__device__ __forceinline__ int reflect101(int g) {
    // valid for g in [-IMG+2, 2*IMG-2): single reflection
    return g < 0 ? -g : (g >= IMG ? 2 * IMG - 2 - g : g);
}

__global__ __launch_bounds__(256, 6) void GaussianBlur_38963943309988_kernel(
    const float* __restrict__ in, float* __restrict__ out, GaussW gw)
{
    // One union buffer, reused: phase 1/2 as raw tile (stride IW=80),
    // phase 2-write/3 as h tile (stride HST=68). 6400 floats = 25.6 KB.
    __shared__ __align__(16) float s_u[IW * IW];

    const int tx  = blockIdx.x;
    const int ty  = blockIdx.y;
    const int img = blockIdx.z;
    const float* __restrict__ src = in  + (size_t)img * IMG * IMG;
    float* __restrict__       dst = out + (size_t)img * IMG * IMG;
    const int x0 = tx * TILE - RAD;
    const int y0 = ty * TILE - RAD;
    const int t  = threadIdx.x;

    // ---------- phase 1: global -> LDS (scaled to [0,255]), unified path ----------
    // chunk idx -> row = idx/20, c4 = idx%20; LDS dest is float offset 4*idx (contiguous).
    for (int idx = t; idx < IW * IW4; idx += 256) {
        const int row = idx / IW4;
        const int c4  = idx - row * IW4;
        const int gy  = reflect101(y0 + row);
        const int gx0 = x0 + 4 * c4;
        const float* rowp = src + (size_t)gy * IMG;
        float4 v;
        if (gx0 >= 0 && gx0 <= IMG - 4) {
            v = *reinterpret_cast<const float4*>(rowp + gx0);   // 16B-aligned
        } else {
            v.x = rowp[reflect101(gx0 + 0)];
            v.y = rowp[reflect101(gx0 + 1)];
            v.z = rowp[reflect101(gx0 + 2)];
            v.w = rowp[reflect101(gx0 + 3)];
        }
        float4 r;
        r.x = (v.x + 1.0f) * 127.5f;
        r.y = (v.y + 1.0f) * 127.5f;
        r.z = (v.z + 1.0f) * 127.5f;
        r.w = (v.w + 1.0f) * 127.5f;
        *reinterpret_cast<float4*>(&s_u[4 * idx]) = r;
    }
    __syncthreads();

    // ---------- phase 2: horizontal blur into REGISTERS (80 rows x 64 cols) ----------
    const int tc = t & 15;    // column group: cols 4tc..4tc+3
    const int tr = t >> 4;    // 0..15
    float4 hreg[5];
    #pragma unroll
    for (int rr = 0; rr < 5; ++rr) {
        const int row = tr + rr * 16;
        const float* rp = &s_u[row * IW + 4 * tc];
        float win[20];
        #pragma unroll
        for (int j = 0; j < 5; ++j) {
            const float4 v = *reinterpret_cast<const float4*>(rp + 4 * j);
            win[4*j+0] = v.x; win[4*j+1] = v.y; win[4*j+2] = v.z; win[4*j+3] = v.w;
        }
        float4 acc = {0.f, 0.f, 0.f, 0.f};
        #pragma unroll
        for (int k = 0; k < KS; ++k) {
            const float w = gw.w[k];
            acc.x += w * win[k+0];
            acc.y += w * win[k+1];
            acc.z += w * win[k+2];
            acc.w += w * win[k+3];
        }
        hreg[rr] = acc;
    }
    __syncthreads();   // all raw reads complete before overwrite

    // write h into the SAME LDS region, padded stride 68 (bank-conflict-free)
    #pragma unroll
    for (int rr = 0; rr < 5; ++rr) {
        const int row = tr + rr * 16;
        *reinterpret_cast<float4*>(&s_u[row * HST + 4 * tc]) = hreg[rr];
    }
    __syncthreads();

    // ---------- phase 3: vertical blur (streaming: 1 read feeds 4 accumulators) ----------
    {
        float4 acc[4];
        #pragma unroll
        for (int rj = 0; rj < 4; ++rj) acc[rj] = make_float4(0.f, 0.f, 0.f, 0.f);
        #pragma unroll
        for (int k = 0; k < 20; ++k) {
            const float4 v = *reinterpret_cast<const float4*>(&s_u[(4 * tr + k) * HST + 4 * tc]);
            #pragma unroll
            for (int rj = 0; rj < 4; ++rj) {
                if (k - rj >= 0 && k - rj < KS) {     // compile-time after unroll
                    const float w = gw.w[k - rj];
                    acc[rj].x += w * v.x;
                    acc[rj].y += w * v.y;
                    acc[rj].z += w * v.z;
                    acc[rj].w += w * v.w;
                }
            }
        }
        const int ox = tx * TILE + 4 * tc;
        #pragma unroll
        for (int rj = 0; rj < 4; ++rj) {
            const int oy = ty * TILE + 4 * tr + rj;
            float4 o;
            o.x = acc[rj].x * (2.0f/255.0f) - (1.0f/255.0f);
            o.y = acc[rj].y * (2.0f/255.0f) - (1.0f/255.0f);
            o.z = acc[rj].z * (2.0f/255.0f) - (1.0f/255.0f);
            o.w = acc[rj].w * (2.0f/255.0f) - (1.0f/255.0f);
            *reinterpret_cast<float4*>(dst + (size_t)oy * IMG + ox) = o;
        }
    }
}

extern "C" void kernel_launch(void* const* d_in, const int* in_sizes, int n_in,
                              void* d_out, int out_size, void* d_ws, size_t ws_size,
                              hipStream_t stream) {
    const float* in = (const float*)d_in[0];
    float* out = (float*)d_out;

    GaussW gw;
    double g[KS], s = 0.0;
    for (int i = 0; i < KS; ++i) {
        const double d = i - (KS - 1) / 2.0;
        g[i] = exp(-(d * d) / 8.0);   // 2*sigma^2 = 8
        s += g[i];
    }
    for (int i = 0; i < KS; ++i) gw.w[i] = (float)(g[i] / s);

    const int nimg = in_sizes[0] / (IMG * IMG);   // 96
    dim3 grid(IMG / TILE, IMG / TILE, nimg);      // (8, 8, 96)
    dim3 block(256);
    hipLaunchKernelGGL(GaussianBlur_38963943309988_kernel, grid, block, 0, stream,
                       in, out, gw);
}

// Round 8
// 189.517 us; speedup vs baseline: 1.1022x; 1.0296x over previous
//
#include <hip/hip_runtime.h>
#include <math.h>

#define TILE 64
#define RAD  8
#define IW   80      // raw tile rows/cols (64 + 2*8)
#define RST  84      // LDS row stride in floats; 84≡20 mod 32 -> 8 consecutive rows hit 8 distinct bank-quads
#define KS   17
#define IMG  512

struct GaussW { float w[KS]; };

__device__ __forceinline__ int reflect101(int g) {
    // valid for g in [-IMG+2, 2*IMG-2): single reflection (cv2 BORDER_DEFAULT)
    return g < 0 ? -g : (g >= IMG ? 2 * IMG - 2 - g : g);
}

__global__ __launch_bounds__(256, 6) void GaussianBlur_38963943309988_kernel(
    const float* __restrict__ in, float* __restrict__ out, GaussW gw)
{
    // Single union buffer: raw 80x80 tile (cols 0..79), later overwritten by
    // h tile (cols 0..63) once every P2 thread holds its window in registers.
    __shared__ __align__(16) float s_u[RST * IW];   // 84*80*4 = 26880 B -> 6 blocks/CU

    const int tx  = blockIdx.x;
    const int ty  = blockIdx.y;
    const int img = blockIdx.z;
    const float* __restrict__ src = in  + (size_t)img * IMG * IMG;
    float* __restrict__       dst = out + (size_t)img * IMG * IMG;
    const int x0 = tx * TILE - RAD;
    const int y0 = ty * TILE - RAD;
    const int t  = threadIdx.x;

    // ---------- P1: global -> LDS, scale to [0,255] ----------
    // 80 rows x 20 float4 chunks = 1600 chunks
    for (int idx = t; idx < IW * (IW/4); idx += 256) {
        const int row = idx / (IW/4);
        const int c4  = idx - row * (IW/4);
        const int gy  = reflect101(y0 + row);
        const int gx0 = x0 + 4 * c4;
        const float* rowp = src + (size_t)gy * IMG;
        float4 v;
        if (gx0 >= 0 && gx0 <= IMG - 4) {
            v = *reinterpret_cast<const float4*>(rowp + gx0);   // 16B-aligned
        } else {
            v.x = rowp[reflect101(gx0 + 0)];
            v.y = rowp[reflect101(gx0 + 1)];
            v.z = rowp[reflect101(gx0 + 2)];
            v.w = rowp[reflect101(gx0 + 3)];
        }
        float4 r;
        r.x = (v.x + 1.0f) * 127.5f;
        r.y = (v.y + 1.0f) * 127.5f;
        r.z = (v.z + 1.0f) * 127.5f;
        r.w = (v.w + 1.0f) * 127.5f;
        *reinterpret_cast<float4*>(&s_u[row * RST + 4 * c4]) = r;
    }
    __syncthreads();

    // ---------- P2a: threads 0..159 load a 48-float row window into registers ----------
    // thread = (row = t%80, seg = t/80); seg covers h cols 32*seg..32*seg+31,
    // which needs raw cols 32*seg..32*seg+47 (17-tap window, raw col = h col + k).
    const int p2row = t % 80;
    const int p2seg = t / 80;        // 0 or 1 for t<160
    float win[48];
    if (t < 160) {
        const float* rp = &s_u[p2row * RST + 32 * p2seg];
        #pragma unroll
        for (int j = 0; j < 12; ++j) {
            const float4 v = *reinterpret_cast<const float4*>(rp + 4 * j);
            win[4*j+0] = v.x; win[4*j+1] = v.y; win[4*j+2] = v.z; win[4*j+3] = v.w;
        }
    }
    __syncthreads();   // all raw reads complete before in-place overwrite

    // ---------- P2b: horizontal blur from registers, write h in place ----------
    if (t < 160) {
        #pragma unroll
        for (int j = 0; j < 8; ++j) {          // 8 float4 outputs = 32 cols
            float4 o = {0.f, 0.f, 0.f, 0.f};
            #pragma unroll
            for (int k = 0; k < KS; ++k) {
                const float w = gw.w[k];
                o.x += w * win[4*j + k + 0];
                o.y += w * win[4*j + k + 1];
                o.z += w * win[4*j + k + 2];
                o.w += w * win[4*j + k + 3];
            }
            *reinterpret_cast<float4*>(&s_u[p2row * RST + 32 * p2seg + 4 * j]) = o;
        }
    }
    __syncthreads();

    // ---------- P3: vertical blur, threads 0..127, rolling over 24 h-rows ----------
    // thread = (c = t&15 -> f4 col, g = t>>4 -> 8-row output segment)
    if (t < 128) {
        const int c = t & 15;
        const int g = t >> 4;        // 0..7
        float4 acc[8];
        #pragma unroll
        for (int r = 0; r < 8; ++r) acc[r] = make_float4(0.f, 0.f, 0.f, 0.f);
        #pragma unroll
        for (int k = 0; k < 24; ++k) {
            const float4 v = *reinterpret_cast<const float4*>(&s_u[(8*g + k) * RST + 4*c]);
            #pragma unroll
            for (int r = 0; r < 8; ++r) {
                if (k - r >= 0 && k - r < KS) {      // compile-time after unroll
                    const float w = gw.w[k - r];
                    acc[r].x += w * v.x;
                    acc[r].y += w * v.y;
                    acc[r].z += w * v.z;
                    acc[r].w += w * v.w;
                }
            }
        }
        const int ox = tx * TILE + 4 * c;
        #pragma unroll
        for (int r = 0; r < 8; ++r) {
            const int oy = ty * TILE + 8 * g + r;
            float4 o;
            o.x = acc[r].x * (2.0f/255.0f) - (1.0f/255.0f);
            o.y = acc[r].y * (2.0f/255.0f) - (1.0f/255.0f);
            o.z = acc[r].z * (2.0f/255.0f) - (1.0f/255.0f);
            o.w = acc[r].w * (2.0f/255.0f) - (1.0f/255.0f);
            *reinterpret_cast<float4*>(dst + (size_t)oy * IMG + ox) = o;
        }
    }
}

extern "C" void kernel_launch(void* const* d_in, const int* in_sizes, int n_in,
                              void* d_out, int out_size, void* d_ws, size_t ws_size,
                              hipStream_t stream) {
    const float* in = (const float*)d_in[0];
    float* out = (float*)d_out;

    GaussW gw;
    double g[KS], s = 0.0;
    for (int i = 0; i < KS; ++i) {
        const double d = i - (KS - 1) / 2.0;
        g[i] = exp(-(d * d) / 8.0);   // 2*sigma^2 = 8
        s += g[i];
    }
    for (int i = 0; i < KS; ++i) gw.w[i] = (float)(g[i] / s);

    const int nimg = in_sizes[0] / (IMG * IMG);   // 96
    dim3 grid(IMG / TILE, IMG / TILE, nimg);      // (8, 8, 96)
    dim3 block(256);
    hipLaunchKernelGGL(GaussianBlur_38963943309988_kernel, grid, block, 0, stream,
                       in, out, gw);
}